// Round 1
// 478.901 us; speedup vs baseline: 1.9244x; 1.9244x over previous
//
#include <hip/hip_runtime.h>
#include <math.h>

#define Dk 1024
#define Ck 32
#define Nk 1024
#define Qk 1024
#define REGP 0.5f
#define NB 64
#define NT (Dk/NB)
#define NROWSV (Qk + Nk + Ck + 1)   // 2081 rows: queries, sorted support, mus, m

// consts layout (floats)
#define CO_KAPPA 0
#define CO_NU    1
#define CO_NJ    2
#define CO_KN    34
#define CO_SCALE 66
#define CO_COMMON 98
#define CO_COEF  130
#define CO_BIASA 162
#define CO_BIASF 200
#define CO_TOTAL 256

// workspace offsets (floats)
#define O_Y    ((size_t)0)
#define O_YO   (O_Y + 2112u*1024u)
#define O_W    (O_YO + 2112u*1024u)
#define O_T    (O_W + 1024u*1024u)
#define O_P    (O_T + 512u*512u)
#define O_MU   (O_P + 1088u*1024u)
#define O_QM   (O_MU + 32u*1024u)
#define O_MB   (O_QM + 32u*1024u)
#define O_MI   (O_MB + 32u*1224u)
#define O_QNY  (O_MI + 32u*1224u)
#define O_QNO  (O_QNY + 1024u)
#define O_MUN  (O_QNO + 1024u)
#define O_GMM  (O_MUN + 32u)
#define O_EX   (O_GMM + 32u)
#define O_CONS (O_EX + 16u)
#define O_CIDX (O_CONS + 256u)

#define WS_DECL \
    float* Y     = Wbuf + O_Y;    (void)Y; \
    float* Yo    = Wbuf + O_YO;   (void)Yo; \
    float* W     = Wbuf + O_W;    (void)W; \
    float* Tb    = Wbuf + O_T;    (void)Tb; \
    float* P     = Wbuf + O_P;    (void)P; \
    float* mu    = Wbuf + O_MU;   (void)mu; \
    float* QM    = Wbuf + O_QM;   (void)QM; \
    float* Mbuf  = Wbuf + O_MB;   (void)Mbuf; \
    float* Minv  = Wbuf + O_MI;   (void)Minv; \
    float* qny   = Wbuf + O_QNY;  (void)qny; \
    float* qno   = Wbuf + O_QNO;  (void)qno; \
    float* mun2o = Wbuf + O_MUN;  (void)mun2o; \
    float* gmm   = Wbuf + O_GMM;  (void)gmm; \
    float* extraf= Wbuf + O_EX;   (void)extraf; \
    float* cons  = Wbuf + O_CONS; (void)cons; \
    int*   cidx  = (int*)(Wbuf + O_CIDX); (void)cidx;

__device__ __forceinline__ float wave_red(float s) {
#pragma unroll
    for (int o = 32; o > 0; o >>= 1) s += __shfl_down(s, o, 64);
    return s;
}

// fetch a 64x64 tile as 4 float4 per thread (independent, batched loads)
__device__ __forceinline__ void fetch4(float4* reg, const float* src, int ld,
                                       int rowbase, int rowmax, int colbase, int t) {
#pragma unroll
    for (int u = 0; u < 4; ++u) {
        int slot = t + u * 256;           // 0..1023
        int r = slot >> 4, c4 = slot & 15;
        int gr = rowbase + r;
        reg[u] = (gr < rowmax) ? *(const float4*)(src + (size_t)gr * ld + colbase + c4 * 4)
                               : make_float4(0.f, 0.f, 0.f, 0.f);
    }
}
// store transposed: dst[k*68 + r] = tile[r][k]
__device__ __forceinline__ void stT(float* dst, const float4* reg, int t) {
#pragma unroll
    for (int u = 0; u < 4; ++u) {
        int slot = t + u * 256;
        int r = slot >> 4, c4 = slot & 15;
        dst[(c4 * 4 + 0) * 68 + r] = reg[u].x;
        dst[(c4 * 4 + 1) * 68 + r] = reg[u].y;
        dst[(c4 * 4 + 2) * 68 + r] = reg[u].z;
        dst[(c4 * 4 + 3) * 68 + r] = reg[u].w;
    }
}
// store straight: dst[r*68 + c] = tile[r][c]  (float4 LDS writes)
__device__ __forceinline__ void stN(float* dst, const float4* reg, int t) {
#pragma unroll
    for (int u = 0; u < 4; ++u) {
        int slot = t + u * 256;
        int r = slot >> 4, c4 = slot & 15;
        *(float4*)(dst + r * 68 + c4 * 4) = reg[u];
    }
}

// acc[r][s] += sum_k At[k][ty*4+r] * Bt[k][tx*4+s]
__device__ __forceinline__ void gemm16(const float* At, const float* Bt,
                                       float acc[4][4], int tx, int ty) {
#pragma unroll 4
    for (int kk = 0; kk < NB; ++kk) {
        float4 a = *(const float4*)(At + kk * 68 + ty * 4);
        float4 b = *(const float4*)(Bt + kk * 68 + tx * 4);
        float av[4] = {a.x, a.y, a.z, a.w};
        float bv[4] = {b.x, b.y, b.z, b.w};
#pragma unroll
        for (int r = 0; r < 4; ++r)
#pragma unroll
            for (int s = 0; s < 4; ++s) acc[r][s] += av[r] * bv[s];
    }
}

// double-buffered k-loop tile GEMM. Per kt: A cols advance by aColStep, rows by aRowStep (same for B).
__device__ __forceinline__ void mm_task(
    const float* aSrc, int aLd, int aRow, int aRowMax, int aCol, int aRowStep, int aColStep,
    const float* bSrc, int bLd, int bRow, int bRowMax, int bCol, int bRowStep, int bColStep,
    bool bTrans, int k0, int k1,
    float acc[4][4], float* smA, float* smB, int t, int tx, int ty)
{
    float4 ra[4], rb[4];
    fetch4(ra, aSrc, aLd, aRow + k0 * aRowStep, aRowMax, aCol + k0 * aColStep, t);
    fetch4(rb, bSrc, bLd, bRow + k0 * bRowStep, bRowMax, bCol + k0 * bColStep, t);
    stT(smA, ra, t);
    if (bTrans) stT(smB, rb, t); else stN(smB, rb, t);
    __syncthreads();
    for (int kt = k0; kt < k1; ++kt) {
        if (kt + 1 < k1) {
            fetch4(ra, aSrc, aLd, aRow + (kt + 1) * aRowStep, aRowMax, aCol + (kt + 1) * aColStep, t);
            fetch4(rb, bSrc, bLd, bRow + (kt + 1) * bRowStep, bRowMax, bCol + (kt + 1) * bColStep, t);
        }
        gemm16(smA, smB, acc, tx, ty);
        __syncthreads();
        if (kt + 1 < k1) {
            stT(smA, ra, t);
            if (bTrans) stT(smB, rb, t); else stN(smB, rb, t);
        }
        __syncthreads();
    }
}

// ========== P0: stats, logdet, diag trtri, zero accum buffers, qno, copies (grid 353) ==========
__global__ __launch_bounds__(256) void k_p0(const float* qx, const int* labels,
                                            const float* mvec, const float* kappa,
                                            const float* nu, const float* td,
                                            const float* tl, float* Wbuf) {
    __shared__ __align__(16) float smem[9216];
    float* smA = smem;
    float* smB = smem + 4352;
    float* sX  = smem + 8704;
    WS_DECL
    const int t = threadIdx.x;
    const int lane = t & 63, wv = t >> 6;
    const int tau = blockIdx.x;

    if (tau == 0) {
        int* scnt = (int*)sX;
        if (t < Ck) scnt[t] = 0;
        __syncthreads();
        for (int n = t; n < Nk; n += 256) {
            int l = labels[n];
            int pos = atomicAdd(&scnt[l], 1);
            cidx[l * Nk + pos] = n;
        }
        __syncthreads();
        if (t < Ck) {
            float kap = fabsf(kappa[0]) + 1e-6f;
            float nu_ = fmaxf(nu[0], (float)(Dk - 1) + 1e-6f);
            float Njf = (float)scnt[t];
            float kN = kap + Njf;
            if (t == 0) { cons[CO_KAPPA] = kap; cons[CO_NU] = nu_; }
            cons[CO_NJ + t] = Njf;
            cons[CO_KN + t] = kN;
            cons[CO_SCALE + t] = (kN + 1.0f) / ((nu_ + Njf - (float)Dk + 1.0f) * kN);
            float common = nu_ + Njf + 1.0f - (float)Dk;
            cons[CO_COMMON + t] = common;
            cons[CO_COEF + t] = 0.5f * (common + (float)Dk);
            cons[CO_BIASA + t] = lgammaf(0.5f * (common + (float)Dk)) - lgammaf(0.5f * common)
                                 - 0.5f * (float)Dk * logf(common);
        }
    } else if (tau == 1) {
        float s = 0.f;
        for (int i = t; i < Dk; i += 256) s += logf(fabsf(td[i]));
        s = wave_red(s);
        if (lane == 0) sX[wv] = s;
        __syncthreads();
        if (t == 0) extraf[0] = 2.f * (sX[0] + sX[1] + sX[2] + sX[3]);
    } else if (tau < 18) {
        int I = tau - 2, b0 = I * NB;
        for (int idx = t; idx < NB * NB; idx += 256) {
            int r = idx >> 6, c = idx & 63;
            float v;
            if (c < r) v = tl[(size_t)(b0 + r) * Dk + b0 + c];
            else if (c == r) v = fabsf(td[b0 + r]);
            else v = 0.f;
            smA[r * 68 + c] = v;
        }
        __syncthreads();
        if (t < NB) {
            int j = t;
            smB[j * 68 + j] = 1.f / smA[j * 68 + j];
            for (int i = j + 1; i < NB; ++i) {
                float s = 0.f;
                for (int k = j; k < i; ++k) s += smA[i * 68 + k] * smB[k * 68 + j];
                smB[i * 68 + j] = -s / smA[i * 68 + i];
            }
        }
        __syncthreads();
        for (int idx = t; idx < NB * NB; idx += 256) {
            int r = idx >> 6, c = idx & 63;
            W[(size_t)(b0 + r) * Dk + b0 + c] = (c <= r) ? smB[r * 68 + c] : 0.f;
        }
    } else if (tau < 150) {        // zero Yo (2112 rows, 16/task)
        int rbase = (tau - 18) * 16;
        for (int j = 0; j < 16; ++j)
            ((float4*)(Yo + (size_t)(rbase + j) * Dk))[t] = make_float4(0, 0, 0, 0);
    } else if (tau < 218) {        // zero P (1088 rows, 16/task)
        int rbase = (tau - 150) * 16;
        for (int j = 0; j < 16; ++j)
            ((float4*)(P + (size_t)(rbase + j) * Qk))[t] = make_float4(0, 0, 0, 0);
    } else if (tau < 220) {        // zero QM (full 32768 floats; was 1/4 coverage before)
        int base = (tau - 218) * 16384;
        for (int k = 0; k < 16; ++k)
            ((float4*)(QM + base + k * 1024))[t] = make_float4(0, 0, 0, 0);
    } else if (tau < 223) {        // zero Mbuf (32*1224 = 39168)
        int base = (tau - 220) * 13056;
        for (int i = t; i < 13056 && base + i < 39168; i += 256) Mbuf[base + i] = 0.f;
    } else if (tau == 223) {       // zero qny, mun2o, gmm
        for (int i = t; i < 1024; i += 256) qny[i] = 0.f;
        if (t < 32) { mun2o[t] = 0.f; gmm[t] = 0.f; }
    } else if (tau < 288) {        // qno (16 rows/task)
        int rbase = (tau - 224) * 16;
        for (int j = wv; j < 16; j += 4) {
            const float* row = qx + (size_t)(rbase + j) * Dk;
            float s = 0.f;
            for (int d = lane; d < Dk; d += 64) { float v = row[d]; s += v * v; }
            s = wave_red(s);
            if (lane == 0) qno[rbase + j] = s;
        }
    } else if (tau < 352) {        // copy queries into Y
        int rbase = (tau - 288) * 16;
        for (int j = 0; j < 16; ++j) {
            int r = rbase + j;
            ((float4*)(Y + (size_t)r * Dk))[t] = ((const float4*)(qx + (size_t)r * Dk))[t];
        }
    } else {                       // m row
        ((float4*)(Y + (size_t)(Qk + Nk + Ck) * Dk))[t] = ((const float4*)mvec)[t];
    }
}

// ========== P1: mu (+Y mu-row +mun2o), sorted-support copy (grid 192) ==========
__global__ __launch_bounds__(256) void k_p1(const float* sx, const float* mvec, float* Wbuf) {
    __shared__ float sX[512];
    WS_DECL
    const int t = threadIdx.x;
    const int lane = t & 63, wv = t >> 6;
    const int tau = blockIdx.x;
    if (tau < 128) {
        int c = tau >> 2;
        int d = ((tau & 3) << 8) + t;
        int Nj = (int)cons[CO_NJ + c];
        float kap = cons[CO_KAPPA], kN = cons[CO_KN + c];
        float acc = 0.f;
        for (int s = 0; s < Nj; ++s) acc += sx[(size_t)cidx[c * Nk + s] * Dk + d];
        float muv = (kap * mvec[d] + acc) / kN;
        mu[c * Dk + d] = muv;
        Y[(size_t)(Qk + Nk + c) * Dk + d] = muv;
        float s2 = wave_red(muv * muv);
        if (lane == 0) sX[wv] = s2;
        __syncthreads();
        if (t == 0) atomicAdd(&mun2o[c], sX[0] + sX[1] + sX[2] + sX[3]);
    } else {
        int rbase = (tau - 128) * 16;
        for (int j = 0; j < 16; ++j) {
            int n = rbase + j;
            int srcrow = cidx[(n >> 5) * Nk + (n & 31)];
            ((float4*)(Y + (size_t)(Qk + n) * Dk))[t] = ((const float4*)(sx + (size_t)srcrow * Dk))[t];
        }
    }
}

// ========== T1: trtri level-1 (merged A+B, local) + QM split-K (grid 72) ==========
__global__ __launch_bounds__(256) void k_t1(const float* tl, const float* qx, float* Wbuf) {
    __shared__ __align__(16) float smem[8704];
    float* smA = smem;
    float* smB = smem + 4352;
    WS_DECL
    const int t = threadIdx.x;
    const int tx = t & 15, ty = t >> 4;
    const int BIG = 1 << 30;
    const int tau = blockIdx.x;
    if (tau < 8) {
        int pb = tau * 128;
        float acc[4][4] = {};
        // T = B * Ainv : At = tl rows pb+64 (T), Bt = W rows pb (N)
        mm_task(tl, Dk, pb + 64, BIG, pb, 0, NB,
                W, Dk, pb, BIG, pb, NB, 0, false, 0, 1,
                acc, smA, smB, t, tx, ty);
        // smB <- T (straight layout), smA <- Cinv transposed
        {
            float4 ra[4];
            fetch4(ra, W, Dk, pb + 64, BIG, pb + 64, t);
#pragma unroll
            for (int r = 0; r < 4; ++r)
#pragma unroll
                for (int s = 0; s < 4; ++s)
                    smB[(ty * 4 + r) * 68 + tx * 4 + s] = acc[r][s];
            stT(smA, ra, t);
        }
        __syncthreads();
        float acc2[4][4] = {};
        gemm16(smA, smB, acc2, tx, ty);
        __syncthreads();
#pragma unroll
        for (int r = 0; r < 4; ++r)
#pragma unroll
            for (int s = 0; s < 4; ++s)
                W[(size_t)(pb + 64 + ty * 4 + r) * Dk + pb + tx * 4 + s] = -acc2[r][s];
    } else {
        int e = tau - 8;
        int qt = e >> 2, kc = e & 3;
        float acc[4][4] = {};
        mm_task(mu, Dk, 0, Ck, 0, 0, NB,
                qx, Dk, qt * NB, Qk, 0, 0, NB, true, kc * 4, kc * 4 + 4,
                acc, smA, smB, t, tx, ty);
#pragma unroll
        for (int r = 0; r < 4; ++r) {
            int c = ty * 4 + r;
            if (c < Ck)
#pragma unroll
                for (int s = 0; s < 4; ++s)
                    atomicAdd(&QM[(size_t)c * Qk + qt * NB + tx * 4 + s], acc[r][s]);
        }
    }
}

// ========== trtri level l phase A: T = B * Ainv (grid pairs*ht*ht) ==========
__global__ __launch_bounds__(256) void k_tr_a(const float* tl, float* Wbuf, int h, int ht) {
    __shared__ __align__(16) float smem[8704];
    float* smA = smem;
    float* smB = smem + 4352;
    WS_DECL
    const int t = threadIdx.x;
    const int tx = t & 15, ty = t >> 4;
    const int BIG = 1 << 30;
    int tau = blockIdx.x;
    int p = tau / (ht * ht), rr = tau % (ht * ht);
    int i = rr / ht, j = rr % ht;
    int pb = p * 2 * h;
    float acc[4][4] = {};
    mm_task(tl, Dk, pb + h + i * NB, BIG, pb, 0, NB,
            W, Dk, pb, BIG, pb + j * NB, NB, 0, false, 0, ht,
            acc, smA, smB, t, tx, ty);
    float* Tp = Tb + (size_t)p * h * h;
#pragma unroll
    for (int r = 0; r < 4; ++r)
#pragma unroll
        for (int s = 0; s < 4; ++s)
            Tp[(size_t)(i * NB + ty * 4 + r) * h + j * NB + tx * 4 + s] = acc[r][s];
}

// ========== trtri level l phase B: W_off = -Cinv * T (grid pairs*ht*ht) ==========
__global__ __launch_bounds__(256) void k_tr_b(float* Wbuf, int h, int ht) {
    __shared__ __align__(16) float smem[8704];
    float* smA = smem;
    float* smB = smem + 4352;
    WS_DECL
    const int t = threadIdx.x;
    const int tx = t & 15, ty = t >> 4;
    const int BIG = 1 << 30;
    int tau = blockIdx.x;
    int p = tau / (ht * ht), rr = tau % (ht * ht);
    int i = rr / ht, j = rr % ht;
    int pb = p * 2 * h;
    const float* Tp = Tb + (size_t)p * h * h;
    float acc[4][4] = {};
    mm_task(W, Dk, pb + h + i * NB, BIG, pb + h, 0, NB,
            Tp, h, 0, BIG, j * NB, NB, 0, false, 0, ht,
            acc, smA, smB, t, tx, ty);
#pragma unroll
    for (int r = 0; r < 4; ++r)
#pragma unroll
        for (int s = 0; s < 4; ++s)
            W[(size_t)(pb + h + i * NB + ty * 4 + r) * Dk + pb + j * NB + tx * 4 + s] = -acc[r][s];
}

// ========== Ygemm split-K: Yo += Y * W^T (grid 1320) ==========
__global__ __launch_bounds__(256) void k_ygemm(float* Wbuf) {
    __shared__ __align__(16) float smem[8704];
    float* smA = smem;
    float* smB = smem + 4352;
    WS_DECL
    const int t = threadIdx.x;
    const int tx = t & 15, ty = t >> 4;
    int e = blockIdx.x;
    int rt = e / 40, w = e - rt * 40;
    int jt, kc;
    if (w < 4) { jt = w; kc = 0; }
    else if (w < 12) { jt = 4 + ((w - 4) >> 1); kc = (w - 4) & 1; }
    else if (w < 24) { jt = 8 + (w - 12) / 3; kc = (w - 12) % 3; }
    else { jt = 12 + ((w - 24) >> 2); kc = (w - 24) & 3; }
    int k0 = kc * 4, k1 = min(jt + 1, k0 + 4);
    float acc[4][4] = {};
    mm_task(Y, Dk, rt * NB, NROWSV, 0, 0, NB,
            W, Dk, jt * NB, 1 << 30, 0, 0, NB, true, k0, k1,
            acc, smA, smB, t, tx, ty);
#pragma unroll
    for (int r = 0; r < 4; ++r) {
        int gr = rt * NB + ty * 4 + r;
        if (gr < NROWSV)
#pragma unroll
            for (int s = 0; s < 4; ++s)
                atomicAdd(&Yo[(size_t)gr * Dk + jt * NB + tx * 4 + s], acc[r][s]);
    }
}

// ========== P4: P split-K (1088), gram split-K (128), qny (64) (grid 1280) ==========
__global__ __launch_bounds__(256) void k_p4(float* Wbuf) {
    __shared__ __align__(16) float smem[8704];
    float* smA = smem;
    float* smB = smem + 4352;
    WS_DECL
    const int t = threadIdx.x;
    const int tx = t & 15, ty = t >> 4;
    const int lane = t & 63, wv = t >> 6;
    const int tau = blockIdx.x;
    if (tau < 1088) {
        int kc = tau & 3, qt = (tau >> 2) & 15, nt = tau >> 6;
        float acc[4][4] = {};
        mm_task(Yo + (size_t)Qk * Dk, Dk, nt * NB, Nk + Ck + 1, 0, 0, NB,
                Yo, Dk, qt * NB, Qk, 0, 0, NB, true, kc * 4, kc * 4 + 4,
                acc, smA, smB, t, tx, ty);
#pragma unroll
        for (int r = 0; r < 4; ++r) {
            int n = nt * NB + ty * 4 + r;
            if (n < Nk + Ck + 1)
#pragma unroll
                for (int s = 0; s < 4; ++s)
                    atomicAdd(&P[(size_t)n * Qk + qt * NB + tx * 4 + s], acc[r][s]);
        }
    } else if (tau < 1216) {
        int g = tau - 1088;
        int c = g >> 2, kc = g & 3;
        float accg[5];
        int iu[5], ju[5];
#pragma unroll
        for (int u = 0; u < 5; ++u) {
            int e = t + u * 256;
            iu[u] = e / 34; ju[u] = e - iu[u] * 34;
            accg[u] = 0.f;
        }
        for (int kt = kc * 4; kt < kc * 4 + 4; ++kt) {
            for (int e2 = t; e2 < 34 * NB; e2 += 256) {
                int i = e2 >> 6, k = e2 & 63;
                int yr = (i < 32) ? (Qk + c * 32 + i) : ((i == 32) ? (Qk + Nk + c) : (Qk + Nk + Ck));
                smA[i * 68 + k] = Yo[(size_t)yr * Dk + kt * NB + k];
            }
            __syncthreads();
#pragma unroll
            for (int u = 0; u < 5; ++u) {
                int e = t + u * 256;
                if (e < 1156) {
                    float s = 0.f;
                    for (int k = 0; k < NB; ++k) s += smA[iu[u] * 68 + k] * smA[ju[u] * 68 + k];
                    accg[u] += s;
                }
            }
            __syncthreads();
        }
#pragma unroll
        for (int u = 0; u < 5; ++u) {
            int e = t + u * 256;
            if (e < 1156)
                atomicAdd(&Mbuf[c * 1224 + iu[u] * 36 + ju[u]], accg[u]);
        }
    } else {
        int rbase = (tau - 1216) * 16;
        for (int j = wv; j < 16; j += 4) {
            const float* row = Yo + (size_t)(rbase + j) * Dk;
            float s = 0.f;
            for (int d = lane; d < Dk; d += 64) { float v = row[d]; s += v * v; }
            s = wave_red(s);
            if (lane == 0) qny[rbase + j] = s;
        }
    }
}

// ========== P5: 34x34 LDL + inverse + bias per class (grid 32) ==========
__global__ __launch_bounds__(256) void k_p5(float* Wbuf) {
    __shared__ float smem[2464];
    float* Ml = smem;          // stride 35
    float* Z  = smem + 1200;   // stride 35
    float* Dv = smem + 2400;
    WS_DECL
    const int t = threadIdx.x;
    const int c = blockIdx.x;
    float kN = cons[CO_KN + c], kap = cons[CO_KAPPA];
    for (int e = t; e < 34 * 34; e += 256) {
        int i = e / 34, j = e - i * 34;
        Ml[i * 35 + j] = Mbuf[c * 1224 + i * 36 + j];
    }
    __syncthreads();
    if (t == 0) {
        gmm[c] = Ml[32 * 35 + 32];
        Ml[32 * 35 + 32] += -1.f / kN;
        Ml[33 * 35 + 33] += 1.f / kap;
    }
    if (t < 32) Ml[t * 35 + t] += 1.f;
    __syncthreads();
    for (int j = 0; j < 34; ++j) {
        if (t == 0) {
            float s = Ml[j * 35 + j];
            for (int k = 0; k < j; ++k) s -= Ml[j * 35 + k] * Ml[j * 35 + k] * Dv[k];
            Dv[j] = s;
        }
        __syncthreads();
        if (t > j && t < 34) {
            float s = Ml[t * 35 + j];
            for (int k = 0; k < j; ++k) s -= Ml[t * 35 + k] * Ml[j * 35 + k] * Dv[k];
            Ml[t * 35 + j] = s / Dv[j];
        }
        __syncthreads();
    }
    if (t < 34) {
        for (int i = 0; i < 34; ++i) {
            float s = (i == t) ? 1.f : 0.f;
            for (int k = 0; k < i; ++k) s -= Ml[i * 35 + k] * Z[k * 35 + t];
            Z[i * 35 + t] = s;
        }
        for (int i = 33; i >= 0; --i) {
            float s = Z[i * 35 + t] / Dv[i];
            for (int k = i + 1; k < 34; ++k) s -= Ml[k * 35 + i] * Z[k * 35 + t];
            Z[i * 35 + t] = s;
        }
    }
    __syncthreads();
    for (int e = t; e < 34 * 34; e += 256) {
        int i = e / 34, j = e - i * 34;
        Minv[c * 1224 + i * 36 + j] = Z[i * 35 + j];
    }
    if (t == 0) {
        float ld = 0.f;
        for (int j = 0; j < 34; ++j) ld += logf(fabsf(Dv[j]));
        float scale = cons[CO_SCALE + c];
        float logdet = (float)Dk * logf(scale) + extraf[0] + logf(kN) + logf(kap) + ld;
        cons[CO_BIASF + c] = cons[CO_BIASA + c] - 0.5f * logdet;
    }
}

// ========== P6: epilogue, (qt, c) tasks (grid 512) ==========
__global__ __launch_bounds__(256) void k_p6(float* Wbuf, float* out) {
    __shared__ __align__(16) float smem[3904];
    float* Mi  = smem;          // stride 35 (1190)
    float* wL  = smem + 1200;   // stride 68 (2312)
    float* gsm = smem + 3520;   // 34
    float* red = smem + 3520 + 128;  // 256
    WS_DECL
    const int t = threadIdx.x;
    const int tau = blockIdx.x;
    int qt = tau >> 5, c = tau & 31;
    for (int e = t; e < 34 * 34; e += 256) {
        int i = e / 34, j = e - i * 34;
        Mi[i * 35 + j] = Minv[c * 1224 + i * 36 + j];
    }
    if (t < 34)
        gsm[t] = (t < 32) ? Mbuf[c * 1224 + t * 36 + 32]
                          : ((t == 32) ? gmm[c] : Mbuf[c * 1224 + 33 * 36 + 32]);
    __syncthreads();
    for (int e = t; e < 34 * NB; e += 256) {
        int i = e >> 6, qq = e & 63;
        int prow = (i < 32) ? (c * 32 + i) : ((i == 32) ? (Nk + c) : (Nk + Ck));
        wL[i * 68 + qq] = P[(size_t)prow * Qk + qt * NB + qq] - gsm[i];
    }
    __syncthreads();
    {
        int q = t & 63, part = t >> 6;
        int start = (part < 2) ? part * 9 : 18 + (part - 2) * 8;
        int cnt = (part < 2) ? 9 : 8;
        float partial = 0.f;
        for (int i = start; i < start + cnt; ++i) {
            float v = 0.f;
            for (int j = 0; j < 34; ++j) v += Mi[i * 35 + j] * wL[j * 68 + q];
            partial += v * wL[i * 68 + q];
        }
        red[part * 64 + q] = partial;
    }
    __syncthreads();
    if (t < 64) {
        int q = t;
        float quad = red[q] + red[64 + q] + red[128 + q] + red[192 + q];
        int qg = qt * NB + q;
        float w32 = wL[32 * 68 + q];
        float ydist2 = qny[qg] - 2.f * w32 - gmm[c];
        float dd = qno[qg] + mun2o[c] - 2.f * QM[(size_t)c * Qk + qg];
        float scale = cons[CO_SCALE + c], common = cons[CO_COMMON + c];
        float dist = (1.f - REGP) / scale * (ydist2 - quad) + REGP * dd;
        out[(size_t)qg * Ck + c] = cons[CO_BIASF + c] - cons[CO_COEF + c] * log1pf(dist / common);
    }
}

extern "C" void kernel_launch(void* const* d_in, const int* in_sizes, int n_in,
                              void* d_out, int out_size, void* d_ws, size_t ws_size,
                              hipStream_t stream) {
    const float* sx = (const float*)d_in[0];
    const float* qx = (const float*)d_in[1];
    const int* labels = (const int*)d_in[2];
    const float* mvec = (const float*)d_in[3];
    const float* kappa = (const float*)d_in[4];
    const float* nu = (const float*)d_in[5];
    const float* td = (const float*)d_in[6];
    const float* tl = (const float*)d_in[7];
    float* W = (float*)d_ws;
    float* out = (float*)d_out;

    hipLaunchKernelGGL(k_p0, dim3(353), dim3(256), 0, stream,
                       qx, labels, mvec, kappa, nu, td, tl, W);
    hipLaunchKernelGGL(k_p1, dim3(192), dim3(256), 0, stream, sx, mvec, W);
    hipLaunchKernelGGL(k_t1, dim3(72), dim3(256), 0, stream, tl, qx, W);
    for (int l = 2; l <= 4; ++l) {
        int h = 32 << l, ht = h >> 6, pairs = 16 >> l;
        int nt = pairs * ht * ht;
        hipLaunchKernelGGL(k_tr_a, dim3(nt), dim3(256), 0, stream, tl, W, h, ht);
        hipLaunchKernelGGL(k_tr_b, dim3(nt), dim3(256), 0, stream, W, h, ht);
    }
    hipLaunchKernelGGL(k_ygemm, dim3(1320), dim3(256), 0, stream, W);
    hipLaunchKernelGGL(k_p4, dim3(1280), dim3(256), 0, stream, W);
    hipLaunchKernelGGL(k_p5, dim3(32), dim3(256), 0, stream, W);
    hipLaunchKernelGGL(k_p6, dim3(512), dim3(256), 0, stream, W, out);
}